// Round 8
// baseline (379.176 us; speedup 1.0000x reference)
//
#include <hip/hip_runtime.h>
#include <hip/hip_bf16.h>

// GCN 2-layer + global_add_pool on MI355X.
// R7 changes:
//  - Sliced, XCD-affine aggregation: node feature table stored as 8 column
//    slices of 32B (slice j = features [16j,16j+16), contiguous 1.6MB array).
//    agg blocks = (slice = blockIdx&7, nodegroup = blockIdx>>3): with
//    round-robin block->XCD dispatch each XCD gathers only its own 1.6MB
//    slice -> L2-resident (R7 counters: 83MB FETCH = 40% L2 miss on the
//    shared 12.8MB table). Wave = 8 edge-slots x 8 feature-pairs; one load
//    gathers 8 edges x 32B; per-node reduce via 3 xor-shuffles (no LDS).
//  - dinv pre-scaled into the table at producers (gemm epilogue, agg1
//    output): deletes the per-edge dinv[src] gather; per edge = 1 broadcast
//    srcs load + 1 table load + 2 FMA. Self-loop = virtual edge idx==c.

typedef _Float16 f16x8 __attribute__((ext_vector_type(8)));
typedef float f32x4 __attribute__((ext_vector_type(4)));

#define BCHUNK 4096

static __device__ __forceinline__ float f16lo(unsigned int u) {
    union { unsigned short s; _Float16 h; } c; c.s = (unsigned short)(u & 0xffff);
    return (float)c.h;
}
static __device__ __forceinline__ float f16hi(unsigned int u) {
    union { unsigned short s; _Float16 h; } c; c.s = (unsigned short)(u >> 16);
    return (float)c.h;
}
static __device__ __forceinline__ unsigned int pack2f16(float x, float y) {
    union { unsigned short s; _Float16 h; } a, b;
    a.h = (_Float16)x; b.h = (_Float16)y;
    return (unsigned int)a.s | ((unsigned int)b.s << 16);
}

// ---------------- bucket binning ----------------

__global__ __launch_bounds__(256) void bin_hist(const int* __restrict__ ei,
                                                int* __restrict__ counts,
                                                int E, int NB, int NBLK) {
    __shared__ int hist[256];
    int t = threadIdx.x, blk = blockIdx.x;
    for (int b = t; b < NB; b += 256) hist[b] = 0;
    __syncthreads();
    int base = blk * BCHUNK;
    int end = min(E, base + BCHUNK);
    for (int e = base + t; e < end; e += 256)
        atomicAdd(&hist[ei[E + e] >> 8], 1);
    __syncthreads();
    for (int b = t; b < NB; b += 256) counts[b * NBLK + blk] = hist[b];
}

__global__ __launch_bounds__(256) void bin_scatter(const int* __restrict__ ei,
                                                   const int* __restrict__ counts,
                                                   unsigned int* __restrict__ bedges,
                                                   int E, int NB, int NBLK) {
    __shared__ int lcur[256];
    int t = threadIdx.x, blk = blockIdx.x;
    for (int b = t; b < NB; b += 256) lcur[b] = counts[b * NBLK + blk];
    __syncthreads();
    int base = blk * BCHUNK;
    int end = min(E, base + BCHUNK);
    for (int e = base + t; e < end; e += 256) {
        int s = ei[e];
        int d = ei[E + e];
        int pos = atomicAdd(&lcur[d >> 8], 1);
        bedges[pos] = (unsigned int)s | ((unsigned int)(d & 255) << 16);
    }
}

// per-bucket degree count via LDS histogram (coalesced cnt write)
__global__ __launch_bounds__(256) void deg_buckets(const unsigned int* __restrict__ bedges,
                                                   const int* __restrict__ counts,
                                                   int* __restrict__ cnt,
                                                   int E, int N, int NB, int NBLK) {
    __shared__ int lcnt[256];
    int b = blockIdx.x, t = threadIdx.x;
    lcnt[t] = 0;
    __syncthreads();
    int bstart = counts[b * NBLK];
    int bend = (b + 1 < NB) ? counts[(b + 1) * NBLK] : E;
    for (int i = bstart + t; i < bend; i += 256)
        atomicAdd(&lcnt[bedges[i] >> 16], 1);
    __syncthreads();
    int node = (b << 8) + t;
    if (node < N) cnt[node] = lcnt[t];
}

// one block per bucket: CSR fill into the bucket's own (L2-local) window
__global__ __launch_bounds__(256) void fill_buckets(const unsigned int* __restrict__ bedges,
                                                    const int* __restrict__ counts,
                                                    const int* __restrict__ row_start,
                                                    int* __restrict__ srcs,
                                                    int E, int N, int NB, int NBLK) {
    __shared__ int lcur[256];
    int b = blockIdx.x, t = threadIdx.x;
    int node = (b << 8) + t;
    lcur[t] = (node < N) ? row_start[node] : 0;
    __syncthreads();
    int bstart = counts[b * NBLK];
    int bend = (b + 1 < NB) ? counts[(b + 1) * NBLK] : E;
    for (int i = bstart + t; i < bend; i += 256) {
        unsigned int p = bedges[i];
        int pos = atomicAdd(&lcur[p >> 16], 1);
        srcs[pos] = (int)(p & 0xffffu);
    }
}

// ---------------- scans ----------------

__global__ void block_sums(const int* __restrict__ data, int* __restrict__ bsum, int n) {
    __shared__ int s[256];
    int base = blockIdx.x * 1024;
    int t = threadIdx.x;
    int v = 0;
#pragma unroll
    for (int i = 0; i < 4; i++) {
        int idx = base + t * 4 + i;
        if (idx < n) v += data[idx];
    }
    s[t] = v;
    __syncthreads();
    for (int off = 128; off > 0; off >>= 1) {
        if (t < off) s[t] += s[t + off];
        __syncthreads();
    }
    if (t == 0) bsum[blockIdx.x] = s[0];
}

// single-wave exclusive scan over nb (<=64) block sums
__global__ void scan_bsum(int* __restrict__ bsum, int nb) {
    int lane = threadIdx.x & 63;
    int v = (lane < nb) ? bsum[lane] : 0;
    int incl = v;
#pragma unroll
    for (int off = 1; off < 64; off *= 2) {
        int u = __shfl_up(incl, off);
        if (lane >= off) incl += u;
    }
    if (lane < nb) bsum[lane] = incl - v;  // exclusive
}

// generic in-place exclusive scan (given block offsets)
__global__ void scan_apply(int* __restrict__ data, const int* __restrict__ bsum, int n) {
    __shared__ int s[256];
    int base = blockIdx.x * 1024;
    int t = threadIdx.x;
    int loc[4];
    int v = 0;
#pragma unroll
    for (int i = 0; i < 4; i++) {
        int idx = base + t * 4 + i;
        loc[i] = (idx < n) ? data[idx] : 0;
        v += loc[i];
    }
    s[t] = v;
    __syncthreads();
    for (int off = 1; off < 256; off *= 2) {
        int u = (t >= off) ? s[t - off] : 0;
        __syncthreads();
        s[t] += u;
        __syncthreads();
    }
    int excl = s[t] - v + bsum[blockIdx.x];
#pragma unroll
    for (int i = 0; i < 4; i++) {
        int idx = base + t * 4 + i;
        if (idx < n) { data[idx] = excl; excl += loc[i]; }
    }
}

// node scan: cnt -> row_start, dinv
__global__ void scan_nodes(const int* __restrict__ cnt, const int* __restrict__ bsum,
                           int* __restrict__ row_start, float* __restrict__ dinv, int n) {
    __shared__ int s[256];
    int base = blockIdx.x * 1024;
    int t = threadIdx.x;
    int loc[4];
    int v = 0;
#pragma unroll
    for (int i = 0; i < 4; i++) {
        int idx = base + t * 4 + i;
        loc[i] = (idx < n) ? cnt[idx] : 0;
        v += loc[i];
    }
    s[t] = v;
    __syncthreads();
    for (int off = 1; off < 256; off *= 2) {
        int u = (t >= off) ? s[t - off] : 0;
        __syncthreads();
        s[t] += u;
        __syncthreads();
    }
    int excl = s[t] - v + bsum[blockIdx.x];
#pragma unroll
    for (int i = 0; i < 4; i++) {
        int idx = base + t * 4 + i;
        if (idx < n) {
            row_start[idx] = excl;
            dinv[idx] = rsqrtf((float)loc[i] + 1.0f);
            excl += loc[i];
        }
    }
}

// ---------------- W fragment prep ----------------
__global__ void wprep(const float* __restrict__ W, _Float16* __restrict__ wfrag) {
    int idx = blockIdx.x * 256 + threadIdx.x;  // 2048 total
    if (idx >= 2048) return;
    int lane = idx & 63;
    int kc = (idx >> 6) & 3;
    int nb = idx >> 8;
    int col = nb * 16 + (lane & 15);
    int krow = kc * 32 + (lane >> 4) * 8;
#pragma unroll
    for (int j = 0; j < 8; j++)
        wfrag[idx * 8 + j] = (_Float16)W[(krow + j) * 128 + col];
}

// ---------------- GEMM: sliced output T[j][row][16] = dinv[row] * (A@W)[row, 16j..] ----------------
__global__ __launch_bounds__(256) void gemm_mfma_f32in(const float* __restrict__ A,
                                                       const _Float16* __restrict__ wfrag,
                                                       const float* __restrict__ dinv,
                                                       _Float16* __restrict__ C, int M) {
    __shared__ _Float16 As[128 * 136];
    int t = threadIdx.x;
    int row0 = blockIdx.x * 128;

    const float4* A4 = (const float4*)A;
#pragma unroll
    for (int it = 0; it < 16; it++) {
        int v = it * 256 + t;
        int row = v >> 5;
        int seg = v & 31;
        float4 val = make_float4(0.f, 0.f, 0.f, 0.f);
        if (row0 + row < M) val = A4[(size_t)(row0 + row) * 32 + seg];
        _Float16* p = &As[row * 136 + seg * 4];
        p[0] = (_Float16)val.x; p[1] = (_Float16)val.y;
        p[2] = (_Float16)val.z; p[3] = (_Float16)val.w;
    }
    __syncthreads();

    int wv = t >> 6;
    int lane = t & 63;
    int lrow = lane & 15;
    int lq = lane >> 4;

    f32x4 acc[2][8];
#pragma unroll
    for (int i = 0; i < 2; i++)
#pragma unroll
        for (int j = 0; j < 8; j++) acc[i][j] = (f32x4){0.f, 0.f, 0.f, 0.f};

#pragma unroll
    for (int kc = 0; kc < 4; kc++) {
        int k0 = kc * 32;
        f16x8 a0 = *((const f16x8*)&As[(wv * 32 + lrow) * 136 + k0 + lq * 8]);
        f16x8 a1 = *((const f16x8*)&As[(wv * 32 + 16 + lrow) * 136 + k0 + lq * 8]);
#pragma unroll
        for (int nb = 0; nb < 8; nb++) {
            f16x8 b = ((const f16x8*)wfrag)[(nb * 4 + kc) * 64 + lane];
            acc[0][nb] = __builtin_amdgcn_mfma_f32_16x16x32_f16(a0, b, acc[0][nb], 0, 0, 0);
            acc[1][nb] = __builtin_amdgcn_mfma_f32_16x16x32_f16(a1, b, acc[1][nb], 0, 0, 0);
        }
    }

    // C/D layout: col = lane&15, row = (lane>>4)*4 + reg. Sliced+prescaled store.
#pragma unroll
    for (int ti = 0; ti < 2; ti++) {
#pragma unroll
        for (int r = 0; r < 4; r++) {
            int row = row0 + wv * 32 + ti * 16 + lq * 4 + r;
            if (row < M) {
                float sc = dinv[row];
#pragma unroll
                for (int nb = 0; nb < 8; nb++)
                    C[((size_t)nb * M + row) * 16 + lrow] = (_Float16)(acc[ti][nb][r] * sc);
            }
        }
    }
}

// ---------------- sliced aggregation ----------------
// Block = (slice j = blockIdx&7, group of 16 nodes). Wave handles 4
// consecutive nodes. lane = edge-slot (lane>>3) x feature-pair (lane&7).
// Table rows pre-scaled by dinv[src]; self-loop = virtual edge idx==c.
// L1: write ob slice = dinv*relu(dn*sum + bias). else: pool partials in
// registers, shuffle-reduce + atomicAdd P on graph change.
template <bool L1>
__global__ __launch_bounds__(256) void agg_sliced(const _Float16* __restrict__ tab,
                                                  const int* __restrict__ srcs,
                                                  const int* __restrict__ row_start,
                                                  const int* __restrict__ cnt,
                                                  const float* __restrict__ dinv,
                                                  const float* __restrict__ bias,
                                                  const int* __restrict__ batch,
                                                  _Float16* __restrict__ obout,
                                                  float* __restrict__ P, int N) {
    int j = blockIdx.x & 7;
    int grp = blockIdx.x >> 3;
    int wv = threadIdx.x >> 6;
    int lane = threadIdx.x & 63;
    int fg = lane & 7;
    int eg = lane >> 3;
    const unsigned int* T = (const unsigned int*)tab + (size_t)j * N * 8;
    float2 bv = make_float2(0.f, 0.f);
    if (L1) bv = ((const float2*)bias)[j * 8 + fg];
    float ppx = 0.f, ppy = 0.f;
    int curg = -1;
    int nbase = grp * 16 + wv * 4;
    for (int k = 0; k < 4; k++) {
        int node = nbase + k;
        if (node >= N) break;
        int s0 = row_start[node];
        int c = cnt[node];
        float dn = dinv[node];
        float ax = 0.f, ay = 0.f;
        for (int e = 0; e <= c; e += 8) {
            int idx = e + eg;
            int si = (idx < c) ? srcs[s0 + idx] : node;
            float m = (idx <= c) ? 1.f : 0.f;
            unsigned int v = T[(size_t)si * 8 + fg];
            ax = fmaf(m, f16lo(v), ax);
            ay = fmaf(m, f16hi(v), ay);
        }
        if (L1) {
            ax += __shfl_xor(ax, 8);  ay += __shfl_xor(ay, 8);
            ax += __shfl_xor(ax, 16); ay += __shfl_xor(ay, 16);
            ax += __shfl_xor(ax, 32); ay += __shfl_xor(ay, 32);
            float ox = dn * fmaxf(fmaf(dn, ax, bv.x), 0.f);
            float oy = dn * fmaxf(fmaf(dn, ay, bv.y), 0.f);
            if (eg == 0)
                ((unsigned int*)obout)[((size_t)j * N + node) * 8 + fg] = pack2f16(ox, oy);
        } else {
            int g = batch[node];
            if (g != curg) {
                if (curg >= 0) {
                    float sx = ppx, sy = ppy;
                    sx += __shfl_xor(sx, 8);  sy += __shfl_xor(sy, 8);
                    sx += __shfl_xor(sx, 16); sy += __shfl_xor(sy, 16);
                    sx += __shfl_xor(sx, 32); sy += __shfl_xor(sy, 32);
                    if (eg == 0) {
                        atomicAdd(&P[curg * 128 + j * 16 + fg * 2 + 0], sx);
                        atomicAdd(&P[curg * 128 + j * 16 + fg * 2 + 1], sy);
                    }
                }
                curg = g;
                ppx = 0.f; ppy = 0.f;
            }
            ppx = fmaf(dn, ax, ppx);
            ppy = fmaf(dn, ay, ppy);
        }
    }
    if (!L1 && curg >= 0) {
        float sx = ppx, sy = ppy;
        sx += __shfl_xor(sx, 8);  sy += __shfl_xor(sy, 8);
        sx += __shfl_xor(sx, 16); sy += __shfl_xor(sy, 16);
        sx += __shfl_xor(sx, 32); sy += __shfl_xor(sy, 32);
        if (eg == 0) {
            atomicAdd(&P[curg * 128 + j * 16 + fg * 2 + 0], sx);
            atomicAdd(&P[curg * 128 + j * 16 + fg * 2 + 1], sy);
        }
    }
}

// ---------------- out = P @ W2 + n_g * b2, one block per graph ----------------
__global__ __launch_bounds__(128) void gemm_small(const float* __restrict__ P,
                                                  const float* __restrict__ W2,
                                                  const float* __restrict__ b2,
                                                  const int* __restrict__ batch,
                                                  float* __restrict__ out, int n) {
    __shared__ float prow[128];
    int g = blockIdx.x;
    int c = threadIdx.x;
    prow[c] = P[g * 128 + c];
    __syncthreads();
    int lo = 0, hi = n;
    while (lo < hi) { int mid = (lo + hi) >> 1; if (batch[mid] < g) lo = mid + 1; else hi = mid; }
    int start = lo;
    hi = n;
    while (lo < hi) { int mid = (lo + hi) >> 1; if (batch[mid] < g + 1) lo = mid + 1; else hi = mid; }
    float ng = (float)(lo - start);
    float acc = 0.f;
#pragma unroll 8
    for (int k = 0; k < 128; k++) acc = fmaf(prow[k], W2[k * 128 + c], acc);
    out[g * 128 + c] = acc + ng * b2[c];
}

extern "C" void kernel_launch(void* const* d_in, const int* in_sizes, int n_in,
                              void* d_out, int out_size, void* d_ws, size_t ws_size,
                              hipStream_t stream) {
    const float* x  = (const float*)d_in[0];
    const int*   ei = (const int*)d_in[1];
    const int*   batch = (const int*)d_in[2];
    const float* W1 = (const float*)d_in[3];
    const float* b1 = (const float*)d_in[4];
    const float* W2 = (const float*)d_in[5];
    const float* b2 = (const float*)d_in[6];
    float* out = (float*)d_out;

    const int N = in_sizes[2];       // 50000 (assumed <= 65536)
    const int E = in_sizes[1] / 2;   // 800000

    const int NB = (N + 255) >> 8;              // 196 buckets
    const int NBLK = (E + BCHUNK - 1) / BCHUNK; // 196 chunks
    const int ncounts = NB * NBLK;              // 38416

    // workspace layout
    _Float16* hb = (_Float16*)d_ws;                  // N*128 halves (sliced)
    _Float16* ob = hb + (size_t)N * 128;             // N*128 halves (sliced)
    int* cnt  = (int*)(ob + (size_t)N * 128);        // N
    int* row_start = cnt + N;                        // N
    float* dinv    = (float*)(row_start + N);        // N
    int* srcs      = (int*)(dinv + N);               // E
    unsigned int* bedges = (unsigned int*)(srcs + E);// E
    int* counts    = (int*)(bedges + E);             // NB*NBLK
    _Float16* wfrag1 = (_Float16*)(counts + ncounts);// 128*128
    float* P       = (float*)(wfrag1 + 128 * 128);   // 128*128 f32
    int* bsum      = (int*)(P + 128 * 128);          // <=64

    const int nbc = (ncounts + 1023) / 1024;  // <=64
    const int nbn = (N + 1023) / 1024;        // <=64

    hipMemsetAsync(P, 0, 128 * 128 * sizeof(float), stream);
    wprep<<<8, 256, 0, stream>>>(W1, wfrag1);

    // --- bucket binning + CSR build ---
    bin_hist<<<NBLK, 256, 0, stream>>>(ei, counts, E, NB, NBLK);
    block_sums<<<nbc, 256, 0, stream>>>(counts, bsum, ncounts);
    scan_bsum<<<1, 64, 0, stream>>>(bsum, nbc);
    scan_apply<<<nbc, 256, 0, stream>>>(counts, bsum, ncounts);
    bin_scatter<<<NBLK, 256, 0, stream>>>(ei, counts, bedges, E, NB, NBLK);
    deg_buckets<<<NB, 256, 0, stream>>>(bedges, counts, cnt, E, N, NB, NBLK);
    block_sums<<<nbn, 256, 0, stream>>>(cnt, bsum, N);
    scan_bsum<<<1, 64, 0, stream>>>(bsum, nbn);
    scan_nodes<<<nbn, 256, 0, stream>>>(cnt, bsum, row_start, dinv, N);
    fill_buckets<<<NB, 256, 0, stream>>>(bedges, counts, row_start, srcs, E, N, NB, NBLK);

    const int gemm_grid = (N + 127) / 128;
    const int agg_grid = ((N + 15) / 16) * 8;

    // layer 1: hb = slices of dinv*(x@W1) ; ob = slices of dinv*relu(dn*sum + b1)
    gemm_mfma_f32in<<<gemm_grid, 256, 0, stream>>>(x, wfrag1, dinv, hb, N);
    agg_sliced<true><<<agg_grid, 256, 0, stream>>>(hb, srcs, row_start, cnt, dinv, b1,
                                                   nullptr, ob, nullptr, N);
    // layer 2 (reordered): P = pool(Â o) ; out = P@W2 + n_g*b2
    agg_sliced<false><<<agg_grid, 256, 0, stream>>>(ob, srcs, row_start, cnt, dinv, nullptr,
                                                    batch, nullptr, P, N);
    gemm_small<<<128, 128, 0, stream>>>(P, W2, b2, batch, out, N);
}

// Round 9
// 357.968 us; speedup vs baseline: 1.0592x; 1.0592x over previous
//
#include <hip/hip_runtime.h>
#include <hip/hip_bf16.h>

// GCN 2-layer + global_add_pool on MI355X.
// R8 changes (fixing R7's regression while keeping its win):
//  - R7 post-mortem: slicing DID make the table L2-resident (FETCH 83->22MB)
//    but 32B slice rows cost 2x line traffic (half-used 64B lines) and the
//    serial edge loop killed MLP -> 137us. Fix: 4 slices x 64B rows
//    (slice working set 3.2MB < 4MB XCD L2; every gather = one fully-used
//    64B line = same line count as R6 full-row), slice = blockIdx&3 for XCD
//    affinity, edge loop unrolled x4 groups (4 independent line-gathers in
//    flight), 1 node/wave (200K waves).
//  - Pool uses R6's block-level LDS reduce (4 nodes/block, ~same graph) ->
//    same atomic volume as R6.

typedef _Float16 f16x8 __attribute__((ext_vector_type(8)));
typedef float f32x4 __attribute__((ext_vector_type(4)));

#define BCHUNK 4096

static __device__ __forceinline__ float f16lo(unsigned int u) {
    union { unsigned short s; _Float16 h; } c; c.s = (unsigned short)(u & 0xffff);
    return (float)c.h;
}
static __device__ __forceinline__ float f16hi(unsigned int u) {
    union { unsigned short s; _Float16 h; } c; c.s = (unsigned short)(u >> 16);
    return (float)c.h;
}
static __device__ __forceinline__ unsigned int pack2f16(float x, float y) {
    union { unsigned short s; _Float16 h; } a, b;
    a.h = (_Float16)x; b.h = (_Float16)y;
    return (unsigned int)a.s | ((unsigned int)b.s << 16);
}

// ---------------- bucket binning ----------------

__global__ __launch_bounds__(256) void bin_hist(const int* __restrict__ ei,
                                                int* __restrict__ counts,
                                                int E, int NB, int NBLK) {
    __shared__ int hist[256];
    int t = threadIdx.x, blk = blockIdx.x;
    for (int b = t; b < NB; b += 256) hist[b] = 0;
    __syncthreads();
    int base = blk * BCHUNK;
    int end = min(E, base + BCHUNK);
    for (int e = base + t; e < end; e += 256)
        atomicAdd(&hist[ei[E + e] >> 8], 1);
    __syncthreads();
    for (int b = t; b < NB; b += 256) counts[b * NBLK + blk] = hist[b];
}

__global__ __launch_bounds__(256) void bin_scatter(const int* __restrict__ ei,
                                                   const int* __restrict__ counts,
                                                   unsigned int* __restrict__ bedges,
                                                   int E, int NB, int NBLK) {
    __shared__ int lcur[256];
    int t = threadIdx.x, blk = blockIdx.x;
    for (int b = t; b < NB; b += 256) lcur[b] = counts[b * NBLK + blk];
    __syncthreads();
    int base = blk * BCHUNK;
    int end = min(E, base + BCHUNK);
    for (int e = base + t; e < end; e += 256) {
        int s = ei[e];
        int d = ei[E + e];
        int pos = atomicAdd(&lcur[d >> 8], 1);
        bedges[pos] = (unsigned int)s | ((unsigned int)(d & 255) << 16);
    }
}

// per-bucket degree count via LDS histogram (coalesced cnt write)
__global__ __launch_bounds__(256) void deg_buckets(const unsigned int* __restrict__ bedges,
                                                   const int* __restrict__ counts,
                                                   int* __restrict__ cnt,
                                                   int E, int N, int NB, int NBLK) {
    __shared__ int lcnt[256];
    int b = blockIdx.x, t = threadIdx.x;
    lcnt[t] = 0;
    __syncthreads();
    int bstart = counts[b * NBLK];
    int bend = (b + 1 < NB) ? counts[(b + 1) * NBLK] : E;
    for (int i = bstart + t; i < bend; i += 256)
        atomicAdd(&lcnt[bedges[i] >> 16], 1);
    __syncthreads();
    int node = (b << 8) + t;
    if (node < N) cnt[node] = lcnt[t];
}

// one block per bucket: CSR fill into the bucket's own (L2-local) window
__global__ __launch_bounds__(256) void fill_buckets(const unsigned int* __restrict__ bedges,
                                                    const int* __restrict__ counts,
                                                    const int* __restrict__ row_start,
                                                    int* __restrict__ srcs,
                                                    int E, int N, int NB, int NBLK) {
    __shared__ int lcur[256];
    int b = blockIdx.x, t = threadIdx.x;
    int node = (b << 8) + t;
    lcur[t] = (node < N) ? row_start[node] : 0;
    __syncthreads();
    int bstart = counts[b * NBLK];
    int bend = (b + 1 < NB) ? counts[(b + 1) * NBLK] : E;
    for (int i = bstart + t; i < bend; i += 256) {
        unsigned int p = bedges[i];
        int pos = atomicAdd(&lcur[p >> 16], 1);
        srcs[pos] = (int)(p & 0xffffu);
    }
}

// ---------------- scans ----------------

__global__ void block_sums(const int* __restrict__ data, int* __restrict__ bsum, int n) {
    __shared__ int s[256];
    int base = blockIdx.x * 1024;
    int t = threadIdx.x;
    int v = 0;
#pragma unroll
    for (int i = 0; i < 4; i++) {
        int idx = base + t * 4 + i;
        if (idx < n) v += data[idx];
    }
    s[t] = v;
    __syncthreads();
    for (int off = 128; off > 0; off >>= 1) {
        if (t < off) s[t] += s[t + off];
        __syncthreads();
    }
    if (t == 0) bsum[blockIdx.x] = s[0];
}

// single-wave exclusive scan over nb (<=64) block sums
__global__ void scan_bsum(int* __restrict__ bsum, int nb) {
    int lane = threadIdx.x & 63;
    int v = (lane < nb) ? bsum[lane] : 0;
    int incl = v;
#pragma unroll
    for (int off = 1; off < 64; off *= 2) {
        int u = __shfl_up(incl, off);
        if (lane >= off) incl += u;
    }
    if (lane < nb) bsum[lane] = incl - v;  // exclusive
}

// generic in-place exclusive scan (given block offsets)
__global__ void scan_apply(int* __restrict__ data, const int* __restrict__ bsum, int n) {
    __shared__ int s[256];
    int base = blockIdx.x * 1024;
    int t = threadIdx.x;
    int loc[4];
    int v = 0;
#pragma unroll
    for (int i = 0; i < 4; i++) {
        int idx = base + t * 4 + i;
        loc[i] = (idx < n) ? data[idx] : 0;
        v += loc[i];
    }
    s[t] = v;
    __syncthreads();
    for (int off = 1; off < 256; off *= 2) {
        int u = (t >= off) ? s[t - off] : 0;
        __syncthreads();
        s[t] += u;
        __syncthreads();
    }
    int excl = s[t] - v + bsum[blockIdx.x];
#pragma unroll
    for (int i = 0; i < 4; i++) {
        int idx = base + t * 4 + i;
        if (idx < n) { data[idx] = excl; excl += loc[i]; }
    }
}

// node scan: cnt -> row_start, dinv
__global__ void scan_nodes(const int* __restrict__ cnt, const int* __restrict__ bsum,
                           int* __restrict__ row_start, float* __restrict__ dinv, int n) {
    __shared__ int s[256];
    int base = blockIdx.x * 1024;
    int t = threadIdx.x;
    int loc[4];
    int v = 0;
#pragma unroll
    for (int i = 0; i < 4; i++) {
        int idx = base + t * 4 + i;
        loc[i] = (idx < n) ? cnt[idx] : 0;
        v += loc[i];
    }
    s[t] = v;
    __syncthreads();
    for (int off = 1; off < 256; off *= 2) {
        int u = (t >= off) ? s[t - off] : 0;
        __syncthreads();
        s[t] += u;
        __syncthreads();
    }
    int excl = s[t] - v + bsum[blockIdx.x];
#pragma unroll
    for (int i = 0; i < 4; i++) {
        int idx = base + t * 4 + i;
        if (idx < n) {
            row_start[idx] = excl;
            dinv[idx] = rsqrtf((float)loc[i] + 1.0f);
            excl += loc[i];
        }
    }
}

// ---------------- W fragment prep ----------------
__global__ void wprep(const float* __restrict__ W, _Float16* __restrict__ wfrag) {
    int idx = blockIdx.x * 256 + threadIdx.x;  // 2048 total
    if (idx >= 2048) return;
    int lane = idx & 63;
    int kc = (idx >> 6) & 3;
    int nb = idx >> 8;
    int col = nb * 16 + (lane & 15);
    int krow = kc * 32 + (lane >> 4) * 8;
#pragma unroll
    for (int j = 0; j < 8; j++)
        wfrag[idx * 8 + j] = (_Float16)W[(krow + j) * 128 + col];
}

// ---------------- GEMM: 4-sliced output T[j][row][32] = dinv[row]*(A@W)[row,32j..] ----------------
__global__ __launch_bounds__(256) void gemm_mfma_f32in(const float* __restrict__ A,
                                                       const _Float16* __restrict__ wfrag,
                                                       const float* __restrict__ dinv,
                                                       _Float16* __restrict__ C, int M) {
    __shared__ _Float16 As[128 * 136];
    int t = threadIdx.x;
    int row0 = blockIdx.x * 128;

    const float4* A4 = (const float4*)A;
#pragma unroll
    for (int it = 0; it < 16; it++) {
        int v = it * 256 + t;
        int row = v >> 5;
        int seg = v & 31;
        float4 val = make_float4(0.f, 0.f, 0.f, 0.f);
        if (row0 + row < M) val = A4[(size_t)(row0 + row) * 32 + seg];
        _Float16* p = &As[row * 136 + seg * 4];
        p[0] = (_Float16)val.x; p[1] = (_Float16)val.y;
        p[2] = (_Float16)val.z; p[3] = (_Float16)val.w;
    }
    __syncthreads();

    int wv = t >> 6;
    int lane = t & 63;
    int lrow = lane & 15;
    int lq = lane >> 4;

    f32x4 acc[2][8];
#pragma unroll
    for (int i = 0; i < 2; i++)
#pragma unroll
        for (int j = 0; j < 8; j++) acc[i][j] = (f32x4){0.f, 0.f, 0.f, 0.f};

#pragma unroll
    for (int kc = 0; kc < 4; kc++) {
        int k0 = kc * 32;
        f16x8 a0 = *((const f16x8*)&As[(wv * 32 + lrow) * 136 + k0 + lq * 8]);
        f16x8 a1 = *((const f16x8*)&As[(wv * 32 + 16 + lrow) * 136 + k0 + lq * 8]);
#pragma unroll
        for (int nb = 0; nb < 8; nb++) {
            f16x8 b = ((const f16x8*)wfrag)[(nb * 4 + kc) * 64 + lane];
            acc[0][nb] = __builtin_amdgcn_mfma_f32_16x16x32_f16(a0, b, acc[0][nb], 0, 0, 0);
            acc[1][nb] = __builtin_amdgcn_mfma_f32_16x16x32_f16(a1, b, acc[1][nb], 0, 0, 0);
        }
    }

    // C/D layout: col = lane&15, row = (lane>>4)*4 + reg.
    // Store into 4-slice layout: slice j = col>>5, within = col&31.
#pragma unroll
    for (int ti = 0; ti < 2; ti++) {
#pragma unroll
        for (int r = 0; r < 4; r++) {
            int row = row0 + wv * 32 + ti * 16 + lq * 4 + r;
            if (row < M) {
                float sc = dinv[row];
#pragma unroll
                for (int nb = 0; nb < 8; nb++) {
                    int col = nb * 16 + lrow;
                    C[((size_t)(col >> 5) * M + row) * 32 + (col & 31)] =
                        (_Float16)(acc[ti][nb][r] * sc);
                }
            }
        }
    }
}

// ---------------- 4-sliced aggregation ----------------
// Block = (slice j = blockIdx&3, group of 4 nodes). One node per wave.
// lane = edge-slot (lane>>4, 4 slots) x feature-uint (lane&15). One slot
// load = one fully-used 64B line. Edge loop: 4 independent slot-loads in
// flight. Table rows pre-scaled by dinv[src]; self-loop = virtual idx==c.
template <bool L1>
__global__ __launch_bounds__(256) void agg4(const _Float16* __restrict__ tab,
                                            const int* __restrict__ srcs,
                                            const int* __restrict__ row_start,
                                            const int* __restrict__ cnt,
                                            const float* __restrict__ dinv,
                                            const float* __restrict__ bias,
                                            const int* __restrict__ batch,
                                            _Float16* __restrict__ obout,
                                            float* __restrict__ P, int N) {
    __shared__ float red[4][32];
    int j = blockIdx.x & 3;
    int grp = blockIdx.x >> 2;
    int wv = threadIdx.x >> 6;
    int lane = threadIdx.x & 63;
    int f = lane & 15;
    int slot = lane >> 4;
    int node = grp * 4 + wv;
    const unsigned int* T = (const unsigned int*)tab + (size_t)j * N * 16;
    float ax = 0.f, ay = 0.f, bx = 0.f, by = 0.f;
    float dn = 0.f;
    if (node < N) {
        int s0 = row_start[node];
        int c = cnt[node];
        dn = dinv[node];
        for (int e = 0; e <= c; e += 16) {
#pragma unroll
            for (int g = 0; g < 4; g++) {
                if (e + g * 4 <= c) {
                    int idx = e + g * 4 + slot;
                    int si = (idx < c) ? srcs[s0 + idx] : node;
                    float m = (idx <= c) ? 1.f : 0.f;
                    unsigned int v = T[(size_t)si * 16 + f];
                    if (g & 1) { bx = fmaf(m, f16lo(v), bx); by = fmaf(m, f16hi(v), by); }
                    else       { ax = fmaf(m, f16lo(v), ax); ay = fmaf(m, f16hi(v), ay); }
                }
            }
        }
        ax += bx; ay += by;
        // reduce across 4 slots (lanes f, f+16, f+32, f+48)
        ax += __shfl_xor(ax, 16); ay += __shfl_xor(ay, 16);
        ax += __shfl_xor(ax, 32); ay += __shfl_xor(ay, 32);
    }
    if (L1) {
        if (node < N && slot == 0) {
            float2 bv = ((const float2*)bias)[j * 16 + f];
            float ox = dn * fmaxf(fmaf(dn, ax, bv.x), 0.f);
            float oy = dn * fmaxf(fmaf(dn, ay, bv.y), 0.f);
            ((unsigned int*)obout)[((size_t)j * N + node) * 16 + f] = pack2f16(ox, oy);
        }
    } else {
        float px = dn * ax, py = dn * ay;  // this node's t-row contribution
        int base = grp * 4;
        int lastn = min(base + 3, N - 1);
        bool uniform = (base + 3 < N) && (batch[base] == batch[lastn]);
        if (uniform) {
            if (slot == 0) { red[wv][f * 2 + 0] = px; red[wv][f * 2 + 1] = py; }
            __syncthreads();
            if (wv == 0 && slot == 0) {
                float sx = red[0][f * 2] + red[1][f * 2] + red[2][f * 2] + red[3][f * 2];
                float sy = red[0][f * 2 + 1] + red[1][f * 2 + 1] + red[2][f * 2 + 1] + red[3][f * 2 + 1];
                int g = batch[base];
                atomicAdd(&P[g * 128 + j * 32 + f * 2 + 0], sx);
                atomicAdd(&P[g * 128 + j * 32 + f * 2 + 1], sy);
            }
        } else if (node < N && slot == 0) {
            int g = batch[node];
            atomicAdd(&P[g * 128 + j * 32 + f * 2 + 0], px);
            atomicAdd(&P[g * 128 + j * 32 + f * 2 + 1], py);
        }
    }
}

// ---------------- out = P @ W2 + n_g * b2, one block per graph ----------------
__global__ __launch_bounds__(128) void gemm_small(const float* __restrict__ P,
                                                  const float* __restrict__ W2,
                                                  const float* __restrict__ b2,
                                                  const int* __restrict__ batch,
                                                  float* __restrict__ out, int n) {
    __shared__ float prow[128];
    int g = blockIdx.x;
    int c = threadIdx.x;
    prow[c] = P[g * 128 + c];
    __syncthreads();
    int lo = 0, hi = n;
    while (lo < hi) { int mid = (lo + hi) >> 1; if (batch[mid] < g) lo = mid + 1; else hi = mid; }
    int start = lo;
    hi = n;
    while (lo < hi) { int mid = (lo + hi) >> 1; if (batch[mid] < g + 1) lo = mid + 1; else hi = mid; }
    float ng = (float)(lo - start);
    float acc = 0.f;
#pragma unroll 8
    for (int k = 0; k < 128; k++) acc = fmaf(prow[k], W2[k * 128 + c], acc);
    out[g * 128 + c] = acc + ng * b2[c];
}

extern "C" void kernel_launch(void* const* d_in, const int* in_sizes, int n_in,
                              void* d_out, int out_size, void* d_ws, size_t ws_size,
                              hipStream_t stream) {
    const float* x  = (const float*)d_in[0];
    const int*   ei = (const int*)d_in[1];
    const int*   batch = (const int*)d_in[2];
    const float* W1 = (const float*)d_in[3];
    const float* b1 = (const float*)d_in[4];
    const float* W2 = (const float*)d_in[5];
    const float* b2 = (const float*)d_in[6];
    float* out = (float*)d_out;

    const int N = in_sizes[2];       // 50000 (assumed <= 65536)
    const int E = in_sizes[1] / 2;   // 800000

    const int NB = (N + 255) >> 8;              // 196 buckets
    const int NBLK = (E + BCHUNK - 1) / BCHUNK; // 196 chunks
    const int ncounts = NB * NBLK;              // 38416

    // workspace layout
    _Float16* hb = (_Float16*)d_ws;                  // N*128 halves (4-sliced)
    _Float16* ob = hb + (size_t)N * 128;             // N*128 halves (4-sliced)
    int* cnt  = (int*)(ob + (size_t)N * 128);        // N
    int* row_start = cnt + N;                        // N
    float* dinv    = (float*)(row_start + N);        // N
    int* srcs      = (int*)(dinv + N);               // E
    unsigned int* bedges = (unsigned int*)(srcs + E);// E
    int* counts    = (int*)(bedges + E);             // NB*NBLK
    _Float16* wfrag1 = (_Float16*)(counts + ncounts);// 128*128
    float* P       = (float*)(wfrag1 + 128 * 128);   // 128*128 f32
    int* bsum      = (int*)(P + 128 * 128);          // <=64

    const int nbc = (ncounts + 1023) / 1024;  // <=64
    const int nbn = (N + 1023) / 1024;        // <=64

    hipMemsetAsync(P, 0, 128 * 128 * sizeof(float), stream);
    wprep<<<8, 256, 0, stream>>>(W1, wfrag1);

    // --- bucket binning + CSR build ---
    bin_hist<<<NBLK, 256, 0, stream>>>(ei, counts, E, NB, NBLK);
    block_sums<<<nbc, 256, 0, stream>>>(counts, bsum, ncounts);
    scan_bsum<<<1, 64, 0, stream>>>(bsum, nbc);
    scan_apply<<<nbc, 256, 0, stream>>>(counts, bsum, ncounts);
    bin_scatter<<<NBLK, 256, 0, stream>>>(ei, counts, bedges, E, NB, NBLK);
    deg_buckets<<<NB, 256, 0, stream>>>(bedges, counts, cnt, E, N, NB, NBLK);
    block_sums<<<nbn, 256, 0, stream>>>(cnt, bsum, N);
    scan_bsum<<<1, 64, 0, stream>>>(bsum, nbn);
    scan_nodes<<<nbn, 256, 0, stream>>>(cnt, bsum, row_start, dinv, N);
    fill_buckets<<<NB, 256, 0, stream>>>(bedges, counts, row_start, srcs, E, N, NB, NBLK);

    const int gemm_grid = (N + 127) / 128;
    const int agg_grid = ((N + 3) / 4) * 4;   // 4 slices x node-groups

    // layer 1: hb = 4-slices of dinv*(x@W1) ; ob = 4-slices of dinv*relu(dn*sum + b1)
    gemm_mfma_f32in<<<gemm_grid, 256, 0, stream>>>(x, wfrag1, dinv, hb, N);
    agg4<true><<<agg_grid, 256, 0, stream>>>(hb, srcs, row_start, cnt, dinv, b1,
                                             nullptr, ob, nullptr, N);
    // layer 2 (reordered): P = pool(Â o) ; out = P@W2 + n_g*b2
    agg4<false><<<agg_grid, 256, 0, stream>>>(ob, srcs, row_start, cnt, dinv, nullptr,
                                              batch, nullptr, P, N);
    gemm_small<<<128, 128, 0, stream>>>(P, W2, b2, batch, out, N);
}

// Round 10
// 237.911 us; speedup vs baseline: 1.5938x; 1.5046x over previous
//
#include <hip/hip_runtime.h>
#include <hip/hip_bf16.h>

// GCN 2-layer + global_add_pool on MI355X.
// R9 changes: REVERT to the R6 structure (best: 236us). R7/R8 slicing made
// the table L2-resident (FETCH 83->27MB) but was latency-bound (4 loads +
// masked FMAs per edge, MLP capped at 4) -> 118-137us/agg vs R6's ~50.
// Kept on top of R6:
//  - dinv prescaled into the table (gemm epilogue, agg1 output): deletes the
//    per-edge dinv[src] gather; per edge = 1 row load + 2 adds; self-loop =
//    add own row.
//  - edge loop unrolled x16 (srcs indices wave-uniform -> SGPRs; 16
//    independent 256B table gathers in flight, was 8).

typedef _Float16 f16x8 __attribute__((ext_vector_type(8)));
typedef float f32x4 __attribute__((ext_vector_type(4)));

#define BCHUNK 4096

static __device__ __forceinline__ float f16lo(unsigned int u) {
    union { unsigned short s; _Float16 h; } c; c.s = (unsigned short)(u & 0xffff);
    return (float)c.h;
}
static __device__ __forceinline__ float f16hi(unsigned int u) {
    union { unsigned short s; _Float16 h; } c; c.s = (unsigned short)(u >> 16);
    return (float)c.h;
}
static __device__ __forceinline__ unsigned int pack2f16(float x, float y) {
    union { unsigned short s; _Float16 h; } a, b;
    a.h = (_Float16)x; b.h = (_Float16)y;
    return (unsigned int)a.s | ((unsigned int)b.s << 16);
}

// ---------------- bucket binning ----------------

__global__ __launch_bounds__(256) void bin_hist(const int* __restrict__ ei,
                                                int* __restrict__ counts,
                                                int E, int NB, int NBLK) {
    __shared__ int hist[256];
    int t = threadIdx.x, blk = blockIdx.x;
    for (int b = t; b < NB; b += 256) hist[b] = 0;
    __syncthreads();
    int base = blk * BCHUNK;
    int end = min(E, base + BCHUNK);
    for (int e = base + t; e < end; e += 256)
        atomicAdd(&hist[ei[E + e] >> 8], 1);
    __syncthreads();
    for (int b = t; b < NB; b += 256) counts[b * NBLK + blk] = hist[b];
}

__global__ __launch_bounds__(256) void bin_scatter(const int* __restrict__ ei,
                                                   const int* __restrict__ counts,
                                                   unsigned int* __restrict__ bedges,
                                                   int E, int NB, int NBLK) {
    __shared__ int lcur[256];
    int t = threadIdx.x, blk = blockIdx.x;
    for (int b = t; b < NB; b += 256) lcur[b] = counts[b * NBLK + blk];
    __syncthreads();
    int base = blk * BCHUNK;
    int end = min(E, base + BCHUNK);
    for (int e = base + t; e < end; e += 256) {
        int s = ei[e];
        int d = ei[E + e];
        int pos = atomicAdd(&lcur[d >> 8], 1);
        bedges[pos] = (unsigned int)s | ((unsigned int)(d & 255) << 16);
    }
}

// per-bucket degree count via LDS histogram (coalesced cnt write)
__global__ __launch_bounds__(256) void deg_buckets(const unsigned int* __restrict__ bedges,
                                                   const int* __restrict__ counts,
                                                   int* __restrict__ cnt,
                                                   int E, int N, int NB, int NBLK) {
    __shared__ int lcnt[256];
    int b = blockIdx.x, t = threadIdx.x;
    lcnt[t] = 0;
    __syncthreads();
    int bstart = counts[b * NBLK];
    int bend = (b + 1 < NB) ? counts[(b + 1) * NBLK] : E;
    for (int i = bstart + t; i < bend; i += 256)
        atomicAdd(&lcnt[bedges[i] >> 16], 1);
    __syncthreads();
    int node = (b << 8) + t;
    if (node < N) cnt[node] = lcnt[t];
}

// one block per bucket: CSR fill into the bucket's own (L2-local) window
__global__ __launch_bounds__(256) void fill_buckets(const unsigned int* __restrict__ bedges,
                                                    const int* __restrict__ counts,
                                                    const int* __restrict__ row_start,
                                                    int* __restrict__ srcs,
                                                    int E, int N, int NB, int NBLK) {
    __shared__ int lcur[256];
    int b = blockIdx.x, t = threadIdx.x;
    int node = (b << 8) + t;
    lcur[t] = (node < N) ? row_start[node] : 0;
    __syncthreads();
    int bstart = counts[b * NBLK];
    int bend = (b + 1 < NB) ? counts[(b + 1) * NBLK] : E;
    for (int i = bstart + t; i < bend; i += 256) {
        unsigned int p = bedges[i];
        int pos = atomicAdd(&lcur[p >> 16], 1);
        srcs[pos] = (int)(p & 0xffffu);
    }
}

// ---------------- scans ----------------

__global__ void block_sums(const int* __restrict__ data, int* __restrict__ bsum, int n) {
    __shared__ int s[256];
    int base = blockIdx.x * 1024;
    int t = threadIdx.x;
    int v = 0;
#pragma unroll
    for (int i = 0; i < 4; i++) {
        int idx = base + t * 4 + i;
        if (idx < n) v += data[idx];
    }
    s[t] = v;
    __syncthreads();
    for (int off = 128; off > 0; off >>= 1) {
        if (t < off) s[t] += s[t + off];
        __syncthreads();
    }
    if (t == 0) bsum[blockIdx.x] = s[0];
}

// single-wave exclusive scan over nb (<=64) block sums
__global__ void scan_bsum(int* __restrict__ bsum, int nb) {
    int lane = threadIdx.x & 63;
    int v = (lane < nb) ? bsum[lane] : 0;
    int incl = v;
#pragma unroll
    for (int off = 1; off < 64; off *= 2) {
        int u = __shfl_up(incl, off);
        if (lane >= off) incl += u;
    }
    if (lane < nb) bsum[lane] = incl - v;  // exclusive
}

// generic in-place exclusive scan (given block offsets)
__global__ void scan_apply(int* __restrict__ data, const int* __restrict__ bsum, int n) {
    __shared__ int s[256];
    int base = blockIdx.x * 1024;
    int t = threadIdx.x;
    int loc[4];
    int v = 0;
#pragma unroll
    for (int i = 0; i < 4; i++) {
        int idx = base + t * 4 + i;
        loc[i] = (idx < n) ? data[idx] : 0;
        v += loc[i];
    }
    s[t] = v;
    __syncthreads();
    for (int off = 1; off < 256; off *= 2) {
        int u = (t >= off) ? s[t - off] : 0;
        __syncthreads();
        s[t] += u;
        __syncthreads();
    }
    int excl = s[t] - v + bsum[blockIdx.x];
#pragma unroll
    for (int i = 0; i < 4; i++) {
        int idx = base + t * 4 + i;
        if (idx < n) { data[idx] = excl; excl += loc[i]; }
    }
}

// node scan: cnt -> row_start, dinv
__global__ void scan_nodes(const int* __restrict__ cnt, const int* __restrict__ bsum,
                           int* __restrict__ row_start, float* __restrict__ dinv, int n) {
    __shared__ int s[256];
    int base = blockIdx.x * 1024;
    int t = threadIdx.x;
    int loc[4];
    int v = 0;
#pragma unroll
    for (int i = 0; i < 4; i++) {
        int idx = base + t * 4 + i;
        loc[i] = (idx < n) ? cnt[idx] : 0;
        v += loc[i];
    }
    s[t] = v;
    __syncthreads();
    for (int off = 1; off < 256; off *= 2) {
        int u = (t >= off) ? s[t - off] : 0;
        __syncthreads();
        s[t] += u;
        __syncthreads();
    }
    int excl = s[t] - v + bsum[blockIdx.x];
#pragma unroll
    for (int i = 0; i < 4; i++) {
        int idx = base + t * 4 + i;
        if (idx < n) {
            row_start[idx] = excl;
            dinv[idx] = rsqrtf((float)loc[i] + 1.0f);
            excl += loc[i];
        }
    }
}

// ---------------- W fragment prep ----------------
__global__ void wprep(const float* __restrict__ W, _Float16* __restrict__ wfrag) {
    int idx = blockIdx.x * 256 + threadIdx.x;  // 2048 total
    if (idx >= 2048) return;
    int lane = idx & 63;
    int kc = (idx >> 6) & 3;
    int nb = idx >> 8;
    int col = nb * 16 + (lane & 15);
    int krow = kc * 32 + (lane >> 4) * 8;
#pragma unroll
    for (int j = 0; j < 8; j++)
        wfrag[idx * 8 + j] = (_Float16)W[(krow + j) * 128 + col];
}

// ---------------- GEMM: C[row][128] = dinv[row] * (A@W)[row], fp16 MFMA ----------------
__global__ __launch_bounds__(256) void gemm_mfma_f32in(const float* __restrict__ A,
                                                       const _Float16* __restrict__ wfrag,
                                                       const float* __restrict__ dinv,
                                                       _Float16* __restrict__ C, int M) {
    __shared__ _Float16 As[128 * 136];
    int t = threadIdx.x;
    int row0 = blockIdx.x * 128;

    const float4* A4 = (const float4*)A;
#pragma unroll
    for (int it = 0; it < 16; it++) {
        int v = it * 256 + t;
        int row = v >> 5;
        int seg = v & 31;
        float4 val = make_float4(0.f, 0.f, 0.f, 0.f);
        if (row0 + row < M) val = A4[(size_t)(row0 + row) * 32 + seg];
        _Float16* p = &As[row * 136 + seg * 4];
        p[0] = (_Float16)val.x; p[1] = (_Float16)val.y;
        p[2] = (_Float16)val.z; p[3] = (_Float16)val.w;
    }
    __syncthreads();

    int wv = t >> 6;
    int lane = t & 63;
    int lrow = lane & 15;
    int lq = lane >> 4;

    f32x4 acc[2][8];
#pragma unroll
    for (int i = 0; i < 2; i++)
#pragma unroll
        for (int j = 0; j < 8; j++) acc[i][j] = (f32x4){0.f, 0.f, 0.f, 0.f};

#pragma unroll
    for (int kc = 0; kc < 4; kc++) {
        int k0 = kc * 32;
        f16x8 a0 = *((const f16x8*)&As[(wv * 32 + lrow) * 136 + k0 + lq * 8]);
        f16x8 a1 = *((const f16x8*)&As[(wv * 32 + 16 + lrow) * 136 + k0 + lq * 8]);
#pragma unroll
        for (int nb = 0; nb < 8; nb++) {
            f16x8 b = ((const f16x8*)wfrag)[(nb * 4 + kc) * 64 + lane];
            acc[0][nb] = __builtin_amdgcn_mfma_f32_16x16x32_f16(a0, b, acc[0][nb], 0, 0, 0);
            acc[1][nb] = __builtin_amdgcn_mfma_f32_16x16x32_f16(a1, b, acc[1][nb], 0, 0, 0);
        }
    }

    // C/D layout: col = lane&15, row = (lane>>4)*4 + reg. Prescaled store.
#pragma unroll
    for (int ti = 0; ti < 2; ti++) {
#pragma unroll
        for (int r = 0; r < 4; r++) {
            int row = row0 + wv * 32 + ti * 16 + lq * 4 + r;
            if (row < M) {
                float sc = dinv[row];
#pragma unroll
                for (int nb = 0; nb < 8; nb++)
                    C[(size_t)row * 128 + nb * 16 + lrow] = (_Float16)(acc[ti][nb][r] * sc);
            }
        }
    }
}

// ---------------- agg: one wave per node, prescaled fp16 table, unroll x16 ----------------
// Table rows already scaled by dinv[src]: per edge = 1 row load + 2 adds.
// Self-loop = add own row. Result row = dn * sum.
// L1: ob[node] = dn * relu(dn*sum + b1)   (prescaled for next layer)
// L2: pool partials; block LDS reduce (4 consecutive nodes, ~same graph) +
//     atomicAdd into P.
template <bool L1>
__global__ __launch_bounds__(256) void agg(const _Float16* __restrict__ tab,
                                           const int* __restrict__ srcs,
                                           const int* __restrict__ row_start,
                                           const int* __restrict__ cnt,
                                           const float* __restrict__ dinv,
                                           const float* __restrict__ bias,
                                           const int* __restrict__ batch,
                                           _Float16* __restrict__ obout,
                                           float* __restrict__ P, int n) {
    __shared__ float red[4][128];
    int wv = threadIdx.x >> 6;
    int lane = threadIdx.x & 63;
    int base = blockIdx.x * 4;
    int node = base + wv;
    const unsigned int* T = (const unsigned int*)tab;
    float ax = 0.f, ay = 0.f, bx = 0.f, by = 0.f;
    float dn = 0.f;
    if (node < n) {
        int s0 = row_start[node];
        int c = cnt[node];
        dn = dinv[node];
        int e = 0;
        for (; e + 16 <= c; e += 16) {
            int si[16];
#pragma unroll
            for (int i = 0; i < 16; i++) si[i] = srcs[s0 + e + i];
            unsigned int v[16];
#pragma unroll
            for (int i = 0; i < 16; i++) v[i] = T[(size_t)si[i] * 64 + lane];
#pragma unroll
            for (int i = 0; i < 16; i++) {
                if (i & 1) { bx += f16lo(v[i]); by += f16hi(v[i]); }
                else       { ax += f16lo(v[i]); ay += f16hi(v[i]); }
            }
        }
        for (; e + 4 <= c; e += 4) {
            int si[4];
#pragma unroll
            for (int i = 0; i < 4; i++) si[i] = srcs[s0 + e + i];
            unsigned int v[4];
#pragma unroll
            for (int i = 0; i < 4; i++) v[i] = T[(size_t)si[i] * 64 + lane];
#pragma unroll
            for (int i = 0; i < 4; i++) {
                if (i & 1) { bx += f16lo(v[i]); by += f16hi(v[i]); }
                else       { ax += f16lo(v[i]); ay += f16hi(v[i]); }
            }
        }
        for (; e < c; e++) {
            unsigned int v = T[(size_t)srcs[s0 + e] * 64 + lane];
            ax += f16lo(v); ay += f16hi(v);
        }
        // self-loop: add own (prescaled) row
        unsigned int hv = T[(size_t)node * 64 + lane];
        ax += f16lo(hv); ay += f16hi(hv);
        ax += bx; ay += by;
    }
    if (L1) {
        if (node < n) {
            float2 bv = ((const float2*)bias)[lane];
            float ox = dn * fmaxf(fmaf(dn, ax, bv.x), 0.f);
            float oy = dn * fmaxf(fmaf(dn, ay, bv.y), 0.f);
            ((unsigned int*)obout)[(size_t)node * 64 + lane] = pack2f16(ox, oy);
        }
    } else {
        float px = dn * ax, py = dn * ay;   // this node's t-row
        int lastn = min(base + 3, n - 1);
        bool uniform = (base + 3 < n) && (batch[base] == batch[lastn]);
        if (uniform) {
            red[wv][lane * 2 + 0] = px;
            red[wv][lane * 2 + 1] = py;
            __syncthreads();
            if (wv == 0) {
                float sx = red[0][lane * 2] + red[1][lane * 2] + red[2][lane * 2] + red[3][lane * 2];
                float sy = red[0][lane * 2 + 1] + red[1][lane * 2 + 1] + red[2][lane * 2 + 1] + red[3][lane * 2 + 1];
                int g = batch[base];
                atomicAdd(&P[g * 128 + lane * 2 + 0], sx);
                atomicAdd(&P[g * 128 + lane * 2 + 1], sy);
            }
        } else if (node < n) {
            int g = batch[node];
            atomicAdd(&P[g * 128 + lane * 2 + 0], px);
            atomicAdd(&P[g * 128 + lane * 2 + 1], py);
        }
    }
}

// ---------------- out = P @ W2 + n_g * b2, one block per graph ----------------
__global__ __launch_bounds__(128) void gemm_small(const float* __restrict__ P,
                                                  const float* __restrict__ W2,
                                                  const float* __restrict__ b2,
                                                  const int* __restrict__ batch,
                                                  float* __restrict__ out, int n) {
    __shared__ float prow[128];
    int g = blockIdx.x;
    int c = threadIdx.x;
    prow[c] = P[g * 128 + c];
    __syncthreads();
    int lo = 0, hi = n;
    while (lo < hi) { int mid = (lo + hi) >> 1; if (batch[mid] < g) lo = mid + 1; else hi = mid; }
    int start = lo;
    hi = n;
    while (lo < hi) { int mid = (lo + hi) >> 1; if (batch[mid] < g + 1) lo = mid + 1; else hi = mid; }
    float ng = (float)(lo - start);
    float acc = 0.f;
#pragma unroll 8
    for (int k = 0; k < 128; k++) acc = fmaf(prow[k], W2[k * 128 + c], acc);
    out[g * 128 + c] = acc + ng * b2[c];
}

extern "C" void kernel_launch(void* const* d_in, const int* in_sizes, int n_in,
                              void* d_out, int out_size, void* d_ws, size_t ws_size,
                              hipStream_t stream) {
    const float* x  = (const float*)d_in[0];
    const int*   ei = (const int*)d_in[1];
    const int*   batch = (const int*)d_in[2];
    const float* W1 = (const float*)d_in[3];
    const float* b1 = (const float*)d_in[4];
    const float* W2 = (const float*)d_in[5];
    const float* b2 = (const float*)d_in[6];
    float* out = (float*)d_out;

    const int N = in_sizes[2];       // 50000 (assumed <= 65536)
    const int E = in_sizes[1] / 2;   // 800000

    const int NB = (N + 255) >> 8;              // 196 buckets
    const int NBLK = (E + BCHUNK - 1) / BCHUNK; // 196 chunks
    const int ncounts = NB * NBLK;              // 38416

    // workspace layout
    _Float16* hb = (_Float16*)d_ws;                  // N*128 halves
    _Float16* ob = hb + (size_t)N * 128;             // N*128 halves
    int* cnt  = (int*)(ob + (size_t)N * 128);        // N
    int* row_start = cnt + N;                        // N
    float* dinv    = (float*)(row_start + N);        // N
    int* srcs      = (int*)(dinv + N);               // E
    unsigned int* bedges = (unsigned int*)(srcs + E);// E
    int* counts    = (int*)(bedges + E);             // NB*NBLK
    _Float16* wfrag1 = (_Float16*)(counts + ncounts);// 128*128
    float* P       = (float*)(wfrag1 + 128 * 128);   // 128*128 f32
    int* bsum      = (int*)(P + 128 * 128);          // <=64

    const int nbc = (ncounts + 1023) / 1024;  // <=64
    const int nbn = (N + 1023) / 1024;        // <=64

    hipMemsetAsync(P, 0, 128 * 128 * sizeof(float), stream);
    wprep<<<8, 256, 0, stream>>>(W1, wfrag1);

    // --- bucket binning + CSR build ---
    bin_hist<<<NBLK, 256, 0, stream>>>(ei, counts, E, NB, NBLK);
    block_sums<<<nbc, 256, 0, stream>>>(counts, bsum, ncounts);
    scan_bsum<<<1, 64, 0, stream>>>(bsum, nbc);
    scan_apply<<<nbc, 256, 0, stream>>>(counts, bsum, ncounts);
    bin_scatter<<<NBLK, 256, 0, stream>>>(ei, counts, bedges, E, NB, NBLK);
    deg_buckets<<<NB, 256, 0, stream>>>(bedges, counts, cnt, E, N, NB, NBLK);
    block_sums<<<nbn, 256, 0, stream>>>(cnt, bsum, N);
    scan_bsum<<<1, 64, 0, stream>>>(bsum, nbn);
    scan_nodes<<<nbn, 256, 0, stream>>>(cnt, bsum, row_start, dinv, N);
    fill_buckets<<<NB, 256, 0, stream>>>(bedges, counts, row_start, srcs, E, N, NB, NBLK);

    const int gemm_grid = (N + 127) / 128;
    const int agg_grid = (N + 3) / 4;

    // layer 1: hb = dinv*(x@W1) ; ob = dinv*relu(dn*sum + b1)
    gemm_mfma_f32in<<<gemm_grid, 256, 0, stream>>>(x, wfrag1, dinv, hb, N);
    agg<true><<<agg_grid, 256, 0, stream>>>(hb, srcs, row_start, cnt, dinv, b1,
                                            nullptr, ob, nullptr, N);
    // layer 2 (reordered): P = pool(Â o) ; out = P@W2 + n_g*b2
    agg<false><<<agg_grid, 256, 0, stream>>>(ob, srcs, row_start, cnt, dinv, nullptr,
                                             batch, nullptr, P, N);
    gemm_small<<<128, 128, 0, stream>>>(P, W2, b2, batch, out, N);
}